// Round 16
// baseline (140.379 us; speedup 1.0000x reference)
//
#include <hip/hip_runtime.h>
#include <hip/hip_bf16.h>

typedef __bf16 bf16x8 __attribute__((ext_vector_type(8)));
typedef __attribute__((ext_vector_type(8))) short short8_t;
typedef __attribute__((ext_vector_type(4))) short short4_t;
typedef __attribute__((ext_vector_type(4))) float f32x4;

#define DEV __device__ __forceinline__

constexpr int Bc = 2, Sc = 2048, Ec = 1024, Hc = 16, Dc = 64;
constexpr int Mc = Bc * Sc;  // 4096
constexpr int NT = Sc / 64;  // 32 k-tiles
constexpr float kQS = (float)((1.0 / (8.0 + 1e-8)) * 1.4426950408889634);

DEV short f2bf(float f) {
  unsigned int u = __builtin_bit_cast(unsigned int, f);
  unsigned int r = u + 0x7fffu + ((u >> 16) & 1u);
  return (short)(r >> 16);
}
DEV short bfc(float f) { __bf16 h = (__bf16)f; return __builtin_bit_cast(short, h); }

DEV float fexp2(float x) {
#if __has_builtin(__builtin_amdgcn_exp2f)
  return __builtin_amdgcn_exp2f(x);
#else
  float r;
  asm("v_exp_f32 %0, %1" : "=v"(r) : "v"(x));
  return r;
#endif
}

DEV void gload16(const short* g, short* lds) {
  __builtin_amdgcn_global_load_lds((const __attribute__((address_space(1))) void*)g,
                                   (__attribute__((address_space(3))) void*)lds, 16, 0, 0);
}

// ---------- merged prep: 4x weight transpose->bf16 + 3x fp32->bf16 convert ----------
struct Prep {
  const float* w[4]; short* wt[4];
  const float* x[3]; short* y[3];
};
__global__ __launch_bounds__(256) void k_prep(Prep a) {
  const int bid = blockIdx.x;
  if (bid < 4096) {
    __shared__ float tile[32][33];
    const int z = bid >> 10, bk = (bid >> 5) & 31, bn = bid & 31;
    const float* w = a.w[z];
    short* wt = a.wt[z];
    int tx = threadIdx.x & 31, ty = threadIdx.x >> 5;
#pragma unroll
    for (int i = 0; i < 4; i++)
      tile[ty + i * 8][tx] = w[(size_t)(bk * 32 + ty + i * 8) * Ec + bn * 32 + tx];
    __syncthreads();
#pragma unroll
    for (int i = 0; i < 4; i++)
      wt[(size_t)(bn * 32 + ty + i * 8) * Ec + bk * 32 + tx] = f2bf(tile[tx][ty + i * 8]);
  } else {
    const int idx = bid - 4096;
    const int z = idx >> 11, c = idx & 2047;
    const float* x = a.x[z];
    short* y = a.y[z];
    size_t i = ((size_t)c * 256 + threadIdx.x) * 8;
    float4 v0 = *(const float4*)(x + i);
    float4 v1 = *(const float4*)(x + i + 4);
    short8_t h;
    h[0] = bfc(v0.x); h[1] = bfc(v0.y); h[2] = bfc(v0.z); h[3] = bfc(v0.w);
    h[4] = bfc(v1.x); h[5] = bfc(v1.y); h[6] = bfc(v1.z); h[7] = bfc(v1.w);
    *(short8_t*)(y + i) = h;
  }
}

// ---------- shared MFMA tile compute for LDS-staged A+B (o-GEMM, 128x128, BK=64) ----------
DEV void gemm_mfma(const short* lA, const short* lB, f32x4 (&acc)[4][4], int lane, int wm, int wn) {
#pragma unroll
  for (int kc = 0; kc < 2; kc++) {
    bf16x8 a[4], b[4];
#pragma unroll
    for (int mf = 0; mf < 4; mf++) {
      int row = wm * 64 + mf * 16 + (lane & 15);
      int ch = (kc * 4 + (lane >> 4)) ^ (row & 7);
      a[mf] = *(const bf16x8*)&lA[row * 64 + (ch << 3)];
    }
#pragma unroll
    for (int nf = 0; nf < 4; nf++) {
      int row = wn * 64 + nf * 16 + (lane & 15);
      int ch = (kc * 4 + (lane >> 4)) ^ (row & 7);
      b[nf] = *(const bf16x8*)&lB[row * 64 + (ch << 3)];
    }
#pragma unroll
    for (int mf = 0; mf < 4; mf++)
#pragma unroll
      for (int nf = 0; nf < 4; nf++)
        acc[mf][nf] = __builtin_amdgcn_mfma_f32_16x16x32_bf16(a[mf], b[nf], acc[mf][nf], 0, 0, 0);
  }
}

// ---------- QKV GEMM: 256x256, BK=32, 4-buf depth-2, FRAGMENT-ORDER LDS (conflict-free) ----------
// LDS tile = [16 ktiles][64 lanes][16B]; gload_lds writes linear; ds_read_b128 stride-1.
struct QKV3 { const short* A[3]; const short* Bt[3]; const float* bias[3]; short* out[3]; };

__global__ __launch_bounds__(512, 2) void k_gemm_qkv(QKV3 args) {
  __shared__ short lA[4][256 * 32];
  __shared__ short lB[4][256 * 32];
  int lin = blockIdx.x;                    // 192 blocks
  lin = (lin & 7) * 24 + (lin >> 3);       // XCD-contiguous (192 = 8*24)
  const int bx = lin & 3, by = (lin >> 2) & 15, z = lin >> 6;
  const short* A = args.A[z];
  const short* Bt = args.Bt[z];
  const float* bias = args.bias[z];
  short* out = args.out[z];
  const int t = threadIdx.x;
  const int m0 = by * 256, n0 = bx * 256;
  const int lane = t & 63, wid = t >> 6;
  const int wr = wid >> 2, wc = wid & 3;   // wave -> (128-row, 64-col) output sub-tile
  const int gs = lane >> 4, l15 = lane & 15;

  f32x4 acc[8][4];
#pragma unroll
  for (int i = 0; i < 8; i++)
#pragma unroll
    for (int j = 0; j < 4; j++) acc[i][j] = {0.f, 0.f, 0.f, 0.f};

  // stage: 16 ktiles (16 rows x 32 k each); wave stages tiles wid*2+j; per-lane source
  // row = tile*16 + l15, k = k0 + gs*8; LDS dest linear (lane i at base + i*16B).
  auto stage = [&](int st, int buf) {
    const int k0 = st * 32;
#pragma unroll
    for (int j = 0; j < 2; j++) {
      int tile = wid * 2 + j;
      int row = tile * 16 + l15;
      gload16(A + (size_t)(m0 + row) * Ec + k0 + gs * 8, &lA[buf][tile * 512]);
      gload16(Bt + (size_t)(n0 + row) * Ec + k0 + gs * 8, &lB[buf][tile * 512]);
    }
  };

  // compute: fragment reads are stride-1 b128 (lane i reads base + i*16B)
  auto compute = [&](int buf) {
    bf16x8 a[8], b[4];
#pragma unroll
    for (int m2 = 0; m2 < 8; m2++)
      a[m2] = *(const bf16x8*)&lA[buf][((wr * 8 + m2) * 64 + lane) * 8];
#pragma unroll
    for (int n2 = 0; n2 < 4; n2++)
      b[n2] = *(const bf16x8*)&lB[buf][((wc * 4 + n2) * 64 + lane) * 8];
#pragma unroll
    for (int m2 = 0; m2 < 8; m2++)
#pragma unroll
      for (int n2 = 0; n2 < 4; n2++)
        acc[m2][n2] = __builtin_amdgcn_mfma_f32_16x16x32_bf16(a[m2], b[n2], acc[m2][n2], 0, 0, 0);
  };

  // prologue: stages 0,1,2 in flight (depth 2 beyond current)
  stage(0, 0);
  stage(1, 1);
  stage(2, 2);
  for (int s = 0; s < 30; s++) {
    asm volatile("s_waitcnt vmcnt(8)" ::: "memory");  // stage(s) landed; 2 stages stay in flight
    __builtin_amdgcn_s_barrier();                      // publish all waves' loads; frees buf[(s-1)&3]
    if (s + 3 < 32) stage(s + 3, (s + 3) & 3);         // WAR-safe post-barrier
    compute(s & 3);
  }
  asm volatile("s_waitcnt vmcnt(4)" ::: "memory");
  __builtin_amdgcn_s_barrier();
  compute(30 & 3);
  asm volatile("s_waitcnt vmcnt(0)" ::: "memory");
  __builtin_amdgcn_s_barrier();
  compute(31 & 3);

#pragma unroll
  for (int mf = 0; mf < 8; mf++) {
#pragma unroll
    for (int nf = 0; nf < 4; nf++) {
      int col = n0 + wc * 64 + nf * 16 + l15;
      float bs = bias[col];
      int row0 = m0 + wr * 128 + mf * 16 + (gs << 2);
      int bh = ((row0 >> 11) << 4) + (col >> 6);
      int d = col & 63;
      size_t bhbase = (size_t)bh * Sc * Dc;
      if (z == 0) {  // Q: [B,H,S,D]
#pragma unroll
        for (int r = 0; r < 4; r++) {
          int row = row0 + r;
          size_t off = bhbase + (size_t)(row & 2047) * Dc + d;
          out[off] = f2bf((acc[mf][nf][r] + bs) * kQS);
        }
      } else if (z == 1) {  // K fragment order (dense)
#pragma unroll
        for (int r = 0; r < 4; r++) {
          int sr = (row0 + r) & 2047;
          size_t off = bhbase + (size_t)(sr >> 4) * 1024 + ((d >> 5) * 512) +
                       (((d >> 3) & 3) * 128) + ((sr & 15) * 8) + (d & 7);
          out[off] = f2bf(acc[mf][nf][r] + bs);
        }
      } else {  // V fragment order (dense)
        short4_t h;
#pragma unroll
        for (int r = 0; r < 4; r++) h[r] = f2bf(acc[mf][nf][r] + bs);
        int s0 = row0 & 2047;
        size_t off = bhbase + (size_t)(s0 >> 6) * 4096 + (((s0 >> 5) & 1) * 2048) +
                     (((d >> 4) & 3) * 512) + ((((s0 >> 3) & 3) * 16 + (d & 15)) * 8) + (s0 & 7);
        *(short4_t*)&out[off] = h;
      }
    }
  }
}

// ---------- out-proj GEMM: counted-vmcnt dbuf (proven R10 schedule, 128x128) ----------
__global__ __launch_bounds__(256, 2) void k_gemm_o(const short* __restrict__ A,
                                                   const short* __restrict__ Bt,
                                                   const float* __restrict__ bias,
                                                   const float* __restrict__ res,
                                                   float* __restrict__ out) {
  __shared__ short lA[2][128 * 64];
  __shared__ short lB[2][128 * 64];
  int lin = blockIdx.x + 8 * blockIdx.y;  // 256 blocks
  lin = (lin & 7) * 32 + (lin >> 3);
  const int bx = lin & 7, by = lin >> 3;
  const int t = threadIdx.x;
  const int m0 = by * 128, n0 = bx * 128;
  const int lane = t & 63, wid = t >> 6;
  const int wm = wid >> 1, wn = wid & 1;
  const int rl = lane >> 3, chs = ((lane & 7) ^ rl) << 3;

  f32x4 acc[4][4];
#pragma unroll
  for (int i = 0; i < 4; i++)
#pragma unroll
    for (int j = 0; j < 4; j++) acc[i][j] = {0.f, 0.f, 0.f, 0.f};

  auto stage = [&](int st, int buf) {
    const int k0 = st * 64;
#pragma unroll
    for (int j = 0; j < 4; j++) {
      int r0 = wid * 32 + j * 8;
      gload16(A + (size_t)(m0 + r0 + rl) * Ec + k0 + chs, &lA[buf][r0 * 64]);
      gload16(Bt + (size_t)(n0 + r0 + rl) * Ec + k0 + chs, &lB[buf][r0 * 64]);
    }
  };
  stage(0, 0);
  stage(1, 1);
  for (int s = 0; s < 15; s++) {
    asm volatile("s_waitcnt vmcnt(8)" ::: "memory");
    __builtin_amdgcn_s_barrier();
    gemm_mfma(lA[s & 1], lB[s & 1], acc, lane, wm, wn);
    __builtin_amdgcn_s_barrier();
    if (s + 2 < 16) stage(s + 2, s & 1);
  }
  asm volatile("s_waitcnt vmcnt(0)" ::: "memory");
  __builtin_amdgcn_s_barrier();
  gemm_mfma(lA[1], lB[1], acc, lane, wm, wn);

#pragma unroll
  for (int mf = 0; mf < 4; mf++) {
#pragma unroll
    for (int nf = 0; nf < 4; nf++) {
      int col = n0 + wn * 64 + nf * 16 + (lane & 15);
      float bs = bias[col];
#pragma unroll
      for (int r = 0; r < 4; r++) {
        int row = m0 + wm * 64 + mf * 16 + ((lane >> 4) << 2) + r;
        out[(size_t)row * Ec + col] = acc[mf][nf][r] + bs + res[(size_t)row * Ec + col];
      }
    }
  }
}

// ---------- flash attention: paired q-tiles share K/V fragment loads ----------
__global__ __launch_bounds__(256, 2) void k_attn8(const short* __restrict__ Qp,
                                                  const short* __restrict__ Kf,
                                                  const short* __restrict__ Vf,
                                                  const int* __restrict__ maskp,
                                                  short* __restrict__ ctx) {
  __shared__ short lP[64 * 64];  // wave-private rows, reused sequentially for B then A tile
  const int lin = blockIdx.x;    // lin&7 == bh&7 (XCD locality)
  const int bh = lin & 31, qi = lin >> 5;
  const int qtA = qi, qtB = NT - 1 - qi;  // per-block MFMA work = const (33 kt-equivalents)
  const int t = threadIdx.x, lane = t & 63, w = t >> 6;
  const int gs = lane >> 4, l15 = lane & 15;
  const bool causal = maskp[0] != 0;
  const int b = bh >> 4, h = bh & 15;
  const size_t base = (size_t)bh * Sc * Dc;
  const int ktend = causal ? qtB : (NT - 1);

  bf16x8 aqA[2], aqB[2];
  {
    const short* qpA = Qp + base + (size_t)(qtA * 64 + w * 16 + l15) * Dc + gs * 8;
    const short* qpB = Qp + base + (size_t)(qtB * 64 + w * 16 + l15) * Dc + gs * 8;
    aqA[0] = *(const bf16x8*)(qpA);
    aqA[1] = *(const bf16x8*)(qpA + 32);
    aqB[0] = *(const bf16x8*)(qpB);
    aqB[1] = *(const bf16x8*)(qpB + 32);
  }
  bf16x8 ones;
#pragma unroll
  for (int j = 0; j < 8; j++) ones[j] = (__bf16)1.0f;

  f32x4 oA[4], oB[4], lsA, lsB;
#pragma unroll
  for (int i = 0; i < 4; i++) {
    oA[i] = {0.f, 0.f, 0.f, 0.f};
    oB[i] = {0.f, 0.f, 0.f, 0.f};
  }
  lsA = {0.f, 0.f, 0.f, 0.f};
  lsB = {0.f, 0.f, 0.f, 0.f};

  const int prow = w * 16 + l15, pswz = l15 & 7;
  short* pw[4];
  const short* pr[2];
#pragma unroll
  for (int mf = 0; mf < 4; mf++)
    pw[mf] = &lP[prow * 64 + (((2 * mf + (gs >> 1)) ^ pswz) << 3) + (gs & 1) * 4];
#pragma unroll
  for (int kc = 0; kc < 2; kc++)
    pr[kc] = &lP[prow * 64 + (((kc * 4 + gs) ^ pswz) << 3)];

  const short* Kb = Kf + base + lane * 8;
  const short* Vb = Vf + base + lane * 8;
  const int qloc = w * 16 + l15;

  bf16x8 kA[2][4], kB[2][4];
#pragma unroll
  for (int mf = 0; mf < 4; mf++) {
    kA[0][mf] = *(const bf16x8*)(Kb + mf * 1024);
    kA[1][mf] = *(const bf16x8*)(Kb + mf * 1024 + 512);
  }

  int kt = 0;
  auto tilepass = [&](const bf16x8 (&kc_)[2][4], const bf16x8 (&vf)[2][4],
                      const bf16x8 (&aq)[2], f32x4 (&oacc)[4], f32x4& lsum, bool diag) {
    f32x4 s[4];
#pragma unroll
    for (int mf = 0; mf < 4; mf++) s[mf] = {0.f, 0.f, 0.f, 0.f};
    __builtin_amdgcn_s_setprio(1);
#pragma unroll
    for (int c2 = 0; c2 < 2; c2++)
#pragma unroll
      for (int mf = 0; mf < 4; mf++)
        s[mf] = __builtin_amdgcn_mfma_f32_16x16x32_bf16(kc_[c2][mf], aq[c2], s[mf], 0, 0, 0);
    __builtin_amdgcn_s_setprio(0);
    if (diag) {
#pragma unroll
      for (int mf = 0; mf < 4; mf++) {
        short4_t hh;
#pragma unroll
        for (int r = 0; r < 4; r++) {
          float p = fexp2(s[mf][r]);
          if ((mf * 16 + gs * 4 + r) > qloc) p = 0.f;
          hh[r] = bfc(p);
        }
        *(short4_t*)pw[mf] = hh;
      }
    } else {
#pragma unroll
      for (int mf = 0; mf < 4; mf++) {
        short4_t hh;
#pragma unroll
        for (int r = 0; r < 4; r++) hh[r] = bfc(fexp2(s[mf][r]));
        *(short4_t*)pw[mf] = hh;
      }
    }
    bf16x8 pa[2];
    pa[0] = *(const bf16x8*)pr[0];
    pa[1] = *(const bf16x8*)pr[1];
    __builtin_amdgcn_s_setprio(1);
#pragma unroll
    for (int c2 = 0; c2 < 2; c2++) {
      lsum = __builtin_amdgcn_mfma_f32_16x16x32_bf16(pa[c2], ones, lsum, 0, 0, 0);
#pragma unroll
      for (int df = 0; df < 4; df++)
        oacc[df] = __builtin_amdgcn_mfma_f32_16x16x32_bf16(pa[c2], vf[c2][df], oacc[df], 0, 0, 0);
    }
    __builtin_amdgcn_s_setprio(0);
  };

  auto body = [&](bf16x8 (&kc_)[2][4], bf16x8 (&kn_)[2][4]) {
    if (kt < ktend) {
      const short* kp = Kb + (kt + 1) * 4096;
#pragma unroll
      for (int mf = 0; mf < 4; mf++) {
        kn_[0][mf] = *(const bf16x8*)(kp + mf * 1024);
        kn_[1][mf] = *(const bf16x8*)(kp + mf * 1024 + 512);
      }
    }
    const short* vp = Vb + kt * 4096;
    bf16x8 vf[2][4];
#pragma unroll
    for (int c2 = 0; c2 < 2; c2++)
#pragma unroll
      for (int df = 0; df < 4; df++)
        vf[c2][df] = *(const bf16x8*)(vp + c2 * 2048 + df * 512);
    __builtin_amdgcn_sched_barrier(0);

    tilepass(kc_, vf, aqB, oB, lsB, causal && (kt == qtB));
    if (!causal || (kt <= qtA))
      tilepass(kc_, vf, aqA, oA, lsA, causal && (kt == qtA));
  };

  while (true) {
    body(kA, kB);
    if (++kt > ktend) break;
    body(kB, kA);
    if (++kt > ktend) break;
  }

#pragma unroll
  for (int r = 0; r < 4; r++) {
    float ibB = 1.0f / lsB[r];
    float ibA = 1.0f / lsA[r];
    int srB = qtB * 64 + w * 16 + (gs << 2) + r;
    int srA = qtA * 64 + w * 16 + (gs << 2) + r;
#pragma unroll
    for (int df = 0; df < 4; df++) {
      int col = h * 64 + df * 16 + l15;
      ctx[(size_t)(b * Sc + srB) * Ec + col] = f2bf(oB[df][r] * ibB);
      ctx[(size_t)(b * Sc + srA) * Ec + col] = f2bf(oA[df][r] * ibA);
    }
  }
}

// ---------- LayerNorm in-place on fp32 [M][E] ----------
__global__ __launch_bounds__(256) void k_ln(float* __restrict__ x,
                                            const float* __restrict__ gamma,
                                            const float* __restrict__ beta) {
  int row = blockIdx.x, t = threadIdx.x;
  float4 v = *(const float4*)(x + (size_t)row * Ec + t * 4);
  float s = v.x + v.y + v.z + v.w;
  float sq = v.x * v.x + v.y * v.y + v.z * v.z + v.w * v.w;
#pragma unroll
  for (int m = 1; m < 64; m <<= 1) {
    s += __shfl_xor(s, m);
    sq += __shfl_xor(sq, m);
  }
  __shared__ float red[8];
  if ((t & 63) == 0) {
    red[t >> 6] = s;
    red[4 + (t >> 6)] = sq;
  }
  __syncthreads();
  s = red[0] + red[1] + red[2] + red[3];
  sq = red[4] + red[5] + red[6] + red[7];
  float mu = s * (1.f / Ec);
  float var = sq * (1.f / Ec) - mu * mu;
  float rstd = rsqrtf(var + 1e-5f);
  float4 g = *(const float4*)(gamma + t * 4);
  float4 bb = *(const float4*)(beta + t * 4);
  v.x = (v.x - mu) * rstd * g.x + bb.x;
  v.y = (v.y - mu) * rstd * g.y + bb.y;
  v.z = (v.z - mu) * rstd * g.z + bb.z;
  v.w = (v.w - mu) * rstd * g.w + bb.w;
  *(float4*)(x + (size_t)row * Ec + t * 4) = v;
}

extern "C" void kernel_launch(void* const* d_in, const int* in_sizes, int n_in,
                              void* d_out, int out_size, void* d_ws, size_t ws_size,
                              hipStream_t stream) {
  const float* q = (const float*)d_in[0];
  const float* k = (const float*)d_in[1];
  const float* v = (const float*)d_in[2];
  const float* wq = (const float*)d_in[3];
  const float* bq = (const float*)d_in[4];
  const float* wk = (const float*)d_in[5];
  const float* bk = (const float*)d_in[6];
  const float* wv = (const float*)d_in[7];
  const float* bv = (const float*)d_in[8];
  const float* wo = (const float*)d_in[9];
  const float* bo = (const float*)d_in[10];
  const float* gamma = (const float*)d_in[11];
  const float* beta = (const float*)d_in[12];
  const int* maskp = (const int*)d_in[13];
  float* out = (float*)d_out;

  short* wtq = (short*)d_ws;
  short* wtk = wtq + (size_t)Ec * Ec;
  short* wtv = wtk + (size_t)Ec * Ec;
  short* wto = wtv + (size_t)Ec * Ec;
  short* Qp = wto + (size_t)Ec * Ec;   // [B,H,S,D] bf16 (pre-scaled by kQS)
  short* Kf = Qp + (size_t)Mc * Ec;    // fragment-order K (dense)
  short* Vf = Kf + (size_t)Mc * Ec;    // fragment-order V (dense)
  short* ctx = Vf + (size_t)Mc * Ec;   // [M][E] bf16

  // bf16 copies of q,k,v live in d_out (dead until k_gemm_o) + ctx slot
  short* xq = (short*)d_out;
  short* xk = xq + (size_t)Mc * Ec;
  short* xv = ctx;

  dim3 tb(256);

  Prep pargs;
  pargs.w[0] = wq; pargs.w[1] = wk; pargs.w[2] = wv; pargs.w[3] = wo;
  pargs.wt[0] = wtq; pargs.wt[1] = wtk; pargs.wt[2] = wtv; pargs.wt[3] = wto;
  pargs.x[0] = q; pargs.x[1] = k; pargs.x[2] = v;
  pargs.y[0] = xq; pargs.y[1] = xk; pargs.y[2] = xv;
  k_prep<<<dim3(4096 + 3 * (Mc * Ec / 2048)), tb, 0, stream>>>(pargs);

  QKV3 gargs;
  gargs.A[0] = xq; gargs.A[1] = xk; gargs.A[2] = xv;
  gargs.Bt[0] = wtq; gargs.Bt[1] = wtk; gargs.Bt[2] = wtv;
  gargs.bias[0] = bq; gargs.bias[1] = bk; gargs.bias[2] = bv;
  gargs.out[0] = Qp; gargs.out[1] = Kf; gargs.out[2] = Vf;
  k_gemm_qkv<<<dim3(192), dim3(512), 0, stream>>>(gargs);

  k_attn8<<<dim3(NT / 2 * Bc * Hc), tb, 0, stream>>>(Qp, Kf, Vf, maskp, ctx);

  k_gemm_o<<<dim3(Ec / 128, Mc / 128), tb, 0, stream>>>(ctx, wto, bo, q, out);

  k_ln<<<dim3(Mc), tb, 0, stream>>>(out, gamma, beta);
}

// Round 17
// 115.193 us; speedup vs baseline: 1.2186x; 1.2186x over previous
//
#include <hip/hip_runtime.h>
#include <hip/hip_bf16.h>

typedef __bf16 bf16x8 __attribute__((ext_vector_type(8)));
typedef __attribute__((ext_vector_type(8))) short short8_t;
typedef __attribute__((ext_vector_type(4))) short short4_t;
typedef __attribute__((ext_vector_type(4))) float f32x4;

#define DEV __device__ __forceinline__

constexpr int Bc = 2, Sc = 2048, Ec = 1024, Hc = 16, Dc = 64;
constexpr int Mc = Bc * Sc;  // 4096
constexpr int NT = Sc / 64;  // 32 k-tiles
constexpr float kQS = (float)((1.0 / (8.0 + 1e-8)) * 1.4426950408889634);

DEV short f2bf(float f) {
  unsigned int u = __builtin_bit_cast(unsigned int, f);
  unsigned int r = u + 0x7fffu + ((u >> 16) & 1u);
  return (short)(r >> 16);
}
DEV short bfc(float f) { __bf16 h = (__bf16)f; return __builtin_bit_cast(short, h); }

DEV float fexp2(float x) {
#if __has_builtin(__builtin_amdgcn_exp2f)
  return __builtin_amdgcn_exp2f(x);
#else
  float r;
  asm("v_exp_f32 %0, %1" : "=v"(r) : "v"(x));
  return r;
#endif
}

DEV void gload16(const short* g, short* lds) {
  __builtin_amdgcn_global_load_lds((const __attribute__((address_space(1))) void*)g,
                                   (__attribute__((address_space(3))) void*)lds, 16, 0, 0);
}

// ---------- merged prep: 4x weight transpose->bf16 + 3x fp32->bf16 convert ----------
struct Prep {
  const float* w[4]; short* wt[4];
  const float* x[3]; short* y[3];
};
__global__ __launch_bounds__(256) void k_prep(Prep a) {
  const int bid = blockIdx.x;
  if (bid < 4096) {
    __shared__ float tile[32][33];
    const int z = bid >> 10, bk = (bid >> 5) & 31, bn = bid & 31;
    const float* w = a.w[z];
    short* wt = a.wt[z];
    int tx = threadIdx.x & 31, ty = threadIdx.x >> 5;
#pragma unroll
    for (int i = 0; i < 4; i++)
      tile[ty + i * 8][tx] = w[(size_t)(bk * 32 + ty + i * 8) * Ec + bn * 32 + tx];
    __syncthreads();
#pragma unroll
    for (int i = 0; i < 4; i++)
      wt[(size_t)(bn * 32 + ty + i * 8) * Ec + bk * 32 + tx] = f2bf(tile[tx][ty + i * 8]);
  } else {
    const int idx = bid - 4096;
    const int z = idx >> 11, c = idx & 2047;
    const float* x = a.x[z];
    short* y = a.y[z];
    size_t i = ((size_t)c * 256 + threadIdx.x) * 8;
    float4 v0 = *(const float4*)(x + i);
    float4 v1 = *(const float4*)(x + i + 4);
    short8_t h;
    h[0] = bfc(v0.x); h[1] = bfc(v0.y); h[2] = bfc(v0.z); h[3] = bfc(v0.w);
    h[4] = bfc(v1.x); h[5] = bfc(v1.y); h[6] = bfc(v1.z); h[7] = bfc(v1.w);
    *(short8_t*)(y + i) = h;
  }
}

// ---------- shared MFMA tile compute for LDS-staged A+B (o-GEMM, 128x128, BK=64) ----------
DEV void gemm_mfma(const short* lA, const short* lB, f32x4 (&acc)[4][4], int lane, int wm, int wn) {
#pragma unroll
  for (int kc = 0; kc < 2; kc++) {
    bf16x8 a[4], b[4];
#pragma unroll
    for (int mf = 0; mf < 4; mf++) {
      int row = wm * 64 + mf * 16 + (lane & 15);
      int ch = (kc * 4 + (lane >> 4)) ^ (row & 7);
      a[mf] = *(const bf16x8*)&lA[row * 64 + (ch << 3)];
    }
#pragma unroll
    for (int nf = 0; nf < 4; nf++) {
      int row = wn * 64 + nf * 16 + (lane & 15);
      int ch = (kc * 4 + (lane >> 4)) ^ (row & 7);
      b[nf] = *(const bf16x8*)&lB[row * 64 + (ch << 3)];
    }
#pragma unroll
    for (int mf = 0; mf < 4; mf++)
#pragma unroll
      for (int nf = 0; nf < 4; nf++)
        acc[mf][nf] = __builtin_amdgcn_mfma_f32_16x16x32_bf16(a[mf], b[nf], acc[mf][nf], 0, 0, 0);
  }
}

// ---------- QKV GEMM: 256x256 tile, 8 waves, counted-vmcnt dbuf (proven R14) ----------
struct QKV3 { const short* A[3]; const short* Bt[3]; const float* bias[3]; short* out[3]; };

__global__ __launch_bounds__(512, 2) void k_gemm_qkv(QKV3 args) {
  __shared__ short lA[2][2][128 * 64];
  __shared__ short lB[2][2][128 * 64];
  int lin = blockIdx.x;                    // 192 blocks
  lin = (lin & 7) * 24 + (lin >> 3);       // XCD-contiguous (192 = 8*24)
  const int bx = lin & 3, by = (lin >> 2) & 15, z = lin >> 6;
  const short* A = args.A[z];
  const short* Bt = args.Bt[z];
  const float* bias = args.bias[z];
  short* out = args.out[z];
  const int t = threadIdx.x;
  const int m0 = by * 256, n0 = bx * 256;
  const int lane = t & 63, wid = t >> 6;
  const int wr = wid >> 2, wc = wid & 3;   // wave -> (128-row, 64-col) output sub-tile
  const int gs = lane >> 4, l15 = lane & 15;
  const int rl = lane >> 3, chs = ((lane & 7) ^ rl) << 3;

  f32x4 acc[8][4];
#pragma unroll
  for (int i = 0; i < 8; i++)
#pragma unroll
    for (int j = 0; j < 4; j++) acc[i][j] = {0.f, 0.f, 0.f, 0.f};

  auto stage4 = [&](int st, int buf) {
    const int k0 = st * 64;
#pragma unroll
    for (int half = 0; half < 2; half++) {
#pragma unroll
      for (int j = 0; j < 2; j++) {
        int r0 = wid * 16 + j * 8;
        gload16(A + (size_t)(m0 + half * 128 + r0 + rl) * Ec + k0 + chs, &lA[buf][half][r0 * 64]);
      }
    }
#pragma unroll
    for (int half = 0; half < 2; half++) {
#pragma unroll
      for (int j = 0; j < 2; j++) {
        int r0 = wid * 16 + j * 8;
        gload16(Bt + (size_t)(n0 + half * 128 + r0 + rl) * Ec + k0 + chs, &lB[buf][half][r0 * 64]);
      }
    }
  };

  auto compute = [&](int buf) {
    const short* hA = lA[buf][wr];
    const short* hB = lB[buf][wc >> 1];
    const int nsub = (wc & 1) * 64;
#pragma unroll
    for (int qm = 0; qm < 2; qm++) {
#pragma unroll
      for (int qn = 0; qn < 2; qn++) {
        bf16x8 a[2][4], b[2][2];
#pragma unroll
        for (int kc = 0; kc < 2; kc++)
#pragma unroll
          for (int m2 = 0; m2 < 4; m2++) {
            int row = qm * 64 + m2 * 16 + l15;
            int ch = (kc * 4 + gs) ^ (row & 7);
            a[kc][m2] = *(const bf16x8*)&hA[row * 64 + (ch << 3)];
          }
#pragma unroll
        for (int kc = 0; kc < 2; kc++)
#pragma unroll
          for (int n2 = 0; n2 < 2; n2++) {
            int row = nsub + qn * 32 + n2 * 16 + l15;
            int ch = (kc * 4 + gs) ^ (row & 7);
            b[kc][n2] = *(const bf16x8*)&hB[row * 64 + (ch << 3)];
          }
#pragma unroll
        for (int kc = 0; kc < 2; kc++)
#pragma unroll
          for (int m2 = 0; m2 < 4; m2++)
#pragma unroll
            for (int n2 = 0; n2 < 2; n2++)
              acc[qm * 4 + m2][qn * 2 + n2] = __builtin_amdgcn_mfma_f32_16x16x32_bf16(
                  a[kc][m2], b[kc][n2], acc[qm * 4 + m2][qn * 2 + n2], 0, 0, 0);
      }
    }
  };

  stage4(0, 0);
  stage4(1, 1);
  for (int s = 0; s < 15; s++) {
    asm volatile("s_waitcnt vmcnt(8)" ::: "memory");
    __builtin_amdgcn_s_barrier();
    compute(s & 1);
    __builtin_amdgcn_s_barrier();
    if (s + 2 < 16) stage4(s + 2, s & 1);
  }
  asm volatile("s_waitcnt vmcnt(0)" ::: "memory");
  __builtin_amdgcn_s_barrier();
  compute(1);

#pragma unroll
  for (int mf = 0; mf < 8; mf++) {
#pragma unroll
    for (int nf = 0; nf < 4; nf++) {
      int col = n0 + wc * 64 + nf * 16 + l15;
      float bs = bias[col];
      int row0 = m0 + wr * 128 + mf * 16 + (gs << 2);
      int bh = ((row0 >> 11) << 4) + (col >> 6);
      int d = col & 63;
      size_t bhbase = (size_t)bh * Sc * Dc;
      if (z == 0) {  // Q: [B,H,S,D]
#pragma unroll
        for (int r = 0; r < 4; r++) {
          int row = row0 + r;
          size_t off = bhbase + (size_t)(row & 2047) * Dc + d;
          out[off] = f2bf((acc[mf][nf][r] + bs) * kQS);
        }
      } else if (z == 1) {  // K fragment order (dense)
#pragma unroll
        for (int r = 0; r < 4; r++) {
          int sr = (row0 + r) & 2047;
          size_t off = bhbase + (size_t)(sr >> 4) * 1024 + ((d >> 5) * 512) +
                       (((d >> 3) & 3) * 128) + ((sr & 15) * 8) + (d & 7);
          out[off] = f2bf(acc[mf][nf][r] + bs);
        }
      } else {  // V fragment order (dense)
        short4_t h;
#pragma unroll
        for (int r = 0; r < 4; r++) h[r] = f2bf(acc[mf][nf][r] + bs);
        int s0 = row0 & 2047;
        size_t off = bhbase + (size_t)(s0 >> 6) * 4096 + (((s0 >> 5) & 1) * 2048) +
                     (((d >> 4) & 3) * 512) + ((((s0 >> 3) & 3) * 16 + (d & 15)) * 8) + (s0 & 7);
        *(short4_t*)&out[off] = h;
      }
    }
  }
}

// ---------- out-proj GEMM: counted-vmcnt dbuf (proven R10 schedule, 128x128) ----------
__global__ __launch_bounds__(256, 2) void k_gemm_o(const short* __restrict__ A,
                                                   const short* __restrict__ Bt,
                                                   const float* __restrict__ bias,
                                                   const float* __restrict__ res,
                                                   float* __restrict__ out) {
  __shared__ short lA[2][128 * 64];
  __shared__ short lB[2][128 * 64];
  int lin = blockIdx.x + 8 * blockIdx.y;  // 256 blocks
  lin = (lin & 7) * 32 + (lin >> 3);
  const int bx = lin & 7, by = lin >> 3;
  const int t = threadIdx.x;
  const int m0 = by * 128, n0 = bx * 128;
  const int lane = t & 63, wid = t >> 6;
  const int wm = wid >> 1, wn = wid & 1;
  const int rl = lane >> 3, chs = ((lane & 7) ^ rl) << 3;

  f32x4 acc[4][4];
#pragma unroll
  for (int i = 0; i < 4; i++)
#pragma unroll
    for (int j = 0; j < 4; j++) acc[i][j] = {0.f, 0.f, 0.f, 0.f};

  auto stage = [&](int st, int buf) {
    const int k0 = st * 64;
#pragma unroll
    for (int j = 0; j < 4; j++) {
      int r0 = wid * 32 + j * 8;
      gload16(A + (size_t)(m0 + r0 + rl) * Ec + k0 + chs, &lA[buf][r0 * 64]);
      gload16(Bt + (size_t)(n0 + r0 + rl) * Ec + k0 + chs, &lB[buf][r0 * 64]);
    }
  };
  stage(0, 0);
  stage(1, 1);
  for (int s = 0; s < 15; s++) {
    asm volatile("s_waitcnt vmcnt(8)" ::: "memory");
    __builtin_amdgcn_s_barrier();
    gemm_mfma(lA[s & 1], lB[s & 1], acc, lane, wm, wn);
    __builtin_amdgcn_s_barrier();
    if (s + 2 < 16) stage(s + 2, s & 1);
  }
  asm volatile("s_waitcnt vmcnt(0)" ::: "memory");
  __builtin_amdgcn_s_barrier();
  gemm_mfma(lA[1], lB[1], acc, lane, wm, wn);

#pragma unroll
  for (int mf = 0; mf < 4; mf++) {
#pragma unroll
    for (int nf = 0; nf < 4; nf++) {
      int col = n0 + wn * 64 + nf * 16 + (lane & 15);
      float bs = bias[col];
#pragma unroll
      for (int r = 0; r < 4; r++) {
        int row = m0 + wm * 64 + mf * 16 + ((lane >> 4) << 2) + r;
        out[(size_t)row * Ec + col] = acc[mf][nf][r] + bs + res[(size_t)row * Ec + col];
      }
    }
  }
}

// ---------- flash attention: paired q-tiles, K AND V register-pipelined ----------
__global__ __launch_bounds__(256, 2) void k_attn9(const short* __restrict__ Qp,
                                                  const short* __restrict__ Kf,
                                                  const short* __restrict__ Vf,
                                                  const int* __restrict__ maskp,
                                                  short* __restrict__ ctx) {
  __shared__ short lP[64 * 64];  // wave-private rows, reused sequentially for B then A tile
  const int lin = blockIdx.x;    // lin&7 == bh&7 (XCD locality)
  const int bh = lin & 31, qi = lin >> 5;
  const int qtA = qi, qtB = NT - 1 - qi;  // per-block MFMA work = const (33 kt-equivalents)
  const int t = threadIdx.x, lane = t & 63, w = t >> 6;
  const int gs = lane >> 4, l15 = lane & 15;
  const bool causal = maskp[0] != 0;
  const int b = bh >> 4, h = bh & 15;
  const size_t base = (size_t)bh * Sc * Dc;
  const int ktend = causal ? qtB : (NT - 1);

  bf16x8 aqA[2], aqB[2];
  {
    const short* qpA = Qp + base + (size_t)(qtA * 64 + w * 16 + l15) * Dc + gs * 8;
    const short* qpB = Qp + base + (size_t)(qtB * 64 + w * 16 + l15) * Dc + gs * 8;
    aqA[0] = *(const bf16x8*)(qpA);
    aqA[1] = *(const bf16x8*)(qpA + 32);
    aqB[0] = *(const bf16x8*)(qpB);
    aqB[1] = *(const bf16x8*)(qpB + 32);
  }
  bf16x8 ones;
#pragma unroll
  for (int j = 0; j < 8; j++) ones[j] = (__bf16)1.0f;

  f32x4 oA[4], oB[4], lsA, lsB;
#pragma unroll
  for (int i = 0; i < 4; i++) {
    oA[i] = {0.f, 0.f, 0.f, 0.f};
    oB[i] = {0.f, 0.f, 0.f, 0.f};
  }
  lsA = {0.f, 0.f, 0.f, 0.f};
  lsB = {0.f, 0.f, 0.f, 0.f};

  const int prow = w * 16 + l15, pswz = l15 & 7;
  short* pw[4];
  const short* pr[2];
#pragma unroll
  for (int mf = 0; mf < 4; mf++)
    pw[mf] = &lP[prow * 64 + (((2 * mf + (gs >> 1)) ^ pswz) << 3) + (gs & 1) * 4];
#pragma unroll
  for (int kc = 0; kc < 2; kc++)
    pr[kc] = &lP[prow * 64 + (((kc * 4 + gs) ^ pswz) << 3)];

  const short* Kb = Kf + base + lane * 8;
  const short* Vb = Vf + base + lane * 8;
  const int qloc = w * 16 + l15;

  // K and V register double-buffers (named sets, static indexing)
  bf16x8 kA[2][4], kB[2][4], vA[2][4], vB[2][4];
#pragma unroll
  for (int mf = 0; mf < 4; mf++) {
    kA[0][mf] = *(const bf16x8*)(Kb + mf * 1024);
    kA[1][mf] = *(const bf16x8*)(Kb + mf * 1024 + 512);
  }
#pragma unroll
  for (int c2 = 0; c2 < 2; c2++)
#pragma unroll
    for (int df = 0; df < 4; df++)
      vA[c2][df] = *(const bf16x8*)(Vb + c2 * 2048 + df * 512);

  int kt = 0;
  auto tilepass = [&](const bf16x8 (&kc_)[2][4], const bf16x8 (&vc_)[2][4],
                      const bf16x8 (&aq)[2], f32x4 (&oacc)[4], f32x4& lsum, bool diag) {
    f32x4 s[4];
#pragma unroll
    for (int mf = 0; mf < 4; mf++) s[mf] = {0.f, 0.f, 0.f, 0.f};
    __builtin_amdgcn_s_setprio(1);
#pragma unroll
    for (int c2 = 0; c2 < 2; c2++)
#pragma unroll
      for (int mf = 0; mf < 4; mf++)
        s[mf] = __builtin_amdgcn_mfma_f32_16x16x32_bf16(kc_[c2][mf], aq[c2], s[mf], 0, 0, 0);
    __builtin_amdgcn_s_setprio(0);
    if (diag) {
#pragma unroll
      for (int mf = 0; mf < 4; mf++) {
        short4_t hh;
#pragma unroll
        for (int r = 0; r < 4; r++) {
          float p = fexp2(s[mf][r]);
          if ((mf * 16 + gs * 4 + r) > qloc) p = 0.f;
          hh[r] = bfc(p);
        }
        *(short4_t*)pw[mf] = hh;
      }
    } else {
#pragma unroll
      for (int mf = 0; mf < 4; mf++) {
        short4_t hh;
#pragma unroll
        for (int r = 0; r < 4; r++) hh[r] = bfc(fexp2(s[mf][r]));
        *(short4_t*)pw[mf] = hh;
      }
    }
    bf16x8 pa[2];
    pa[0] = *(const bf16x8*)pr[0];
    pa[1] = *(const bf16x8*)pr[1];
    __builtin_amdgcn_s_setprio(1);
#pragma unroll
    for (int c2 = 0; c2 < 2; c2++) {
      lsum = __builtin_amdgcn_mfma_f32_16x16x32_bf16(pa[c2], ones, lsum, 0, 0, 0);
#pragma unroll
      for (int df = 0; df < 4; df++)
        oacc[df] = __builtin_amdgcn_mfma_f32_16x16x32_bf16(pa[c2], vc_[c2][df], oacc[df], 0, 0, 0);
    }
    __builtin_amdgcn_s_setprio(0);
  };

  auto body = [&](bf16x8 (&kc_)[2][4], bf16x8 (&kn_)[2][4],
                  bf16x8 (&vc_)[2][4], bf16x8 (&vn_)[2][4]) {
    if (kt < ktend) {
      const short* kp = Kb + (kt + 1) * 4096;
      const short* vp = Vb + (kt + 1) * 4096;
#pragma unroll
      for (int mf = 0; mf < 4; mf++) {
        kn_[0][mf] = *(const bf16x8*)(kp + mf * 1024);
        kn_[1][mf] = *(const bf16x8*)(kp + mf * 1024 + 512);
      }
#pragma unroll
      for (int c2 = 0; c2 < 2; c2++)
#pragma unroll
        for (int df = 0; df < 4; df++)
          vn_[c2][df] = *(const bf16x8*)(vp + c2 * 2048 + df * 512);
    }
    __builtin_amdgcn_sched_barrier(0);  // pin: prefetch issues stay above compute

    tilepass(kc_, vc_, aqB, oB, lsB, causal && (kt == qtB));
    if (!causal || (kt <= qtA))
      tilepass(kc_, vc_, aqA, oA, lsA, causal && (kt == qtA));
  };

  while (true) {
    body(kA, kB, vA, vB);
    if (++kt > ktend) break;
    body(kB, kA, vB, vA);
    if (++kt > ktend) break;
  }

#pragma unroll
  for (int r = 0; r < 4; r++) {
    float ibB = 1.0f / lsB[r];
    float ibA = 1.0f / lsA[r];
    int srB = qtB * 64 + w * 16 + (gs << 2) + r;
    int srA = qtA * 64 + w * 16 + (gs << 2) + r;
#pragma unroll
    for (int df = 0; df < 4; df++) {
      int col = h * 64 + df * 16 + l15;
      ctx[(size_t)(b * Sc + srB) * Ec + col] = f2bf(oB[df][r] * ibB);
      ctx[(size_t)(b * Sc + srA) * Ec + col] = f2bf(oA[df][r] * ibA);
    }
  }
}

// ---------- LayerNorm in-place on fp32 [M][E] ----------
__global__ __launch_bounds__(256) void k_ln(float* __restrict__ x,
                                            const float* __restrict__ gamma,
                                            const float* __restrict__ beta) {
  int row = blockIdx.x, t = threadIdx.x;
  float4 v = *(const float4*)(x + (size_t)row * Ec + t * 4);
  float s = v.x + v.y + v.z + v.w;
  float sq = v.x * v.x + v.y * v.y + v.z * v.z + v.w * v.w;
#pragma unroll
  for (int m = 1; m < 64; m <<= 1) {
    s += __shfl_xor(s, m);
    sq += __shfl_xor(sq, m);
  }
  __shared__ float red[8];
  if ((t & 63) == 0) {
    red[t >> 6] = s;
    red[4 + (t >> 6)] = sq;
  }
  __syncthreads();
  s = red[0] + red[1] + red[2] + red[3];
  sq = red[4] + red[5] + red[6] + red[7];
  float mu = s * (1.f / Ec);
  float var = sq * (1.f / Ec) - mu * mu;
  float rstd = rsqrtf(var + 1e-5f);
  float4 g = *(const float4*)(gamma + t * 4);
  float4 bb = *(const float4*)(beta + t * 4);
  v.x = (v.x - mu) * rstd * g.x + bb.x;
  v.y = (v.y - mu) * rstd * g.y + bb.y;
  v.z = (v.z - mu) * rstd * g.z + bb.z;
  v.w = (v.w - mu) * rstd * g.w + bb.w;
  *(float4*)(x + (size_t)row * Ec + t * 4) = v;
}

extern "C" void kernel_launch(void* const* d_in, const int* in_sizes, int n_in,
                              void* d_out, int out_size, void* d_ws, size_t ws_size,
                              hipStream_t stream) {
  const float* q = (const float*)d_in[0];
  const float* k = (const float*)d_in[1];
  const float* v = (const float*)d_in[2];
  const float* wq = (const float*)d_in[3];
  const float* bq = (const float*)d_in[4];
  const float* wk = (const float*)d_in[5];
  const float* bk = (const float*)d_in[6];
  const float* wv = (const float*)d_in[7];
  const float* bv = (const float*)d_in[8];
  const float* wo = (const float*)d_in[9];
  const float* bo = (const float*)d_in[10];
  const float* gamma = (const float*)d_in[11];
  const float* beta = (const float*)d_in[12];
  const int* maskp = (const int*)d_in[13];
  float* out = (float*)d_out;

  short* wtq = (short*)d_ws;
  short* wtk = wtq + (size_t)Ec * Ec;
  short* wtv = wtk + (size_t)Ec * Ec;
  short* wto = wtv + (size_t)Ec * Ec;
  short* Qp = wto + (size_t)Ec * Ec;   // [B,H,S,D] bf16 (pre-scaled by kQS)
  short* Kf = Qp + (size_t)Mc * Ec;    // fragment-order K (dense)
  short* Vf = Kf + (size_t)Mc * Ec;    // fragment-order V (dense)
  short* ctx = Vf + (size_t)Mc * Ec;   // [M][E] bf16

  // bf16 copies of q,k,v live in d_out (dead until k_gemm_o) + ctx slot
  short* xq = (short*)d_out;
  short* xk = xq + (size_t)Mc * Ec;
  short* xv = ctx;

  dim3 tb(256);

  Prep pargs;
  pargs.w[0] = wq; pargs.w[1] = wk; pargs.w[2] = wv; pargs.w[3] = wo;
  pargs.wt[0] = wtq; pargs.wt[1] = wtk; pargs.wt[2] = wtv; pargs.wt[3] = wto;
  pargs.x[0] = q; pargs.x[1] = k; pargs.x[2] = v;
  pargs.y[0] = xq; pargs.y[1] = xk; pargs.y[2] = xv;
  k_prep<<<dim3(4096 + 3 * (Mc * Ec / 2048)), tb, 0, stream>>>(pargs);

  QKV3 gargs;
  gargs.A[0] = xq; gargs.A[1] = xk; gargs.A[2] = xv;
  gargs.Bt[0] = wtq; gargs.Bt[1] = wtk; gargs.Bt[2] = wtv;
  gargs.bias[0] = bq; gargs.bias[1] = bk; gargs.bias[2] = bv;
  gargs.out[0] = Qp; gargs.out[1] = Kf; gargs.out[2] = Vf;
  k_gemm_qkv<<<dim3(192), dim3(512), 0, stream>>>(gargs);

  k_attn9<<<dim3(NT / 2 * Bc * Hc), tb, 0, stream>>>(Qp, Kf, Vf, maskp, ctx);

  k_gemm_o<<<dim3(Ec / 128, Mc / 128), tb, 0, stream>>>(ctx, wto, bo, q, out);

  k_ln<<<dim3(Mc), tb, 0, stream>>>(out, gamma, beta);
}